// Round 12
// baseline (230.159 us; speedup 1.0000x reference)
//
#include <hip/hip_runtime.h>
#include <math.h>

// Problem constants
#define NB 1024     // nodes
#define FB 32       // F_IN
#define TB 24       // T
#define GB 64       // F_OUT
#define BB 8        // batch
#define EB 16384    // edges
#define MB 32768    // N*F
#define DB 768      // F*T
#define BTB 192     // B*T
#define WSP 6144    // BT*F width of node-major T matrices

typedef __attribute__((ext_vector_type(8))) short sh8;     // 8 bf16 (4 VGPRs)
typedef __attribute__((ext_vector_type(4))) float f32x4;   // MFMA accumulator

__device__ __forceinline__ float wsum(float v){
  #pragma unroll
  for (int o = 32; o; o >>= 1) v += __shfl_down(v, o);
  return v;
}
__device__ __forceinline__ float wmax(float v){
  #pragma unroll
  for (int o = 32; o; o >>= 1) v = fmaxf(v, __shfl_down(v, o));
  return v;
}
__device__ __forceinline__ float sigm(float v){ return 1.f / (1.f + expf(-v)); }
__device__ __forceinline__ float b2f(unsigned short u){ unsigned int t = ((unsigned int)u) << 16; return __uint_as_float(t); }
__device__ __forceinline__ unsigned short f2b(float f){
  unsigned int u = __float_as_uint(f);
  u += 0x7fffu + ((u >> 16) & 1u);
  return (unsigned short)(u >> 16);
}
__device__ __forceinline__ void gload16(const void* g, void* l){
  typedef const __attribute__((address_space(1))) unsigned int* gp_t;
  typedef __attribute__((address_space(3))) unsigned int* lp_t;
  __builtin_amdgcn_global_load_lds((gp_t)g, (lp_t)l, 16, 0, 0);
}

// ---------------- fused pass 1: x -> xTn (node-major bf16) + Gram partials ----------------
__global__ __launch_bounds__(256) void k_pass1(const float* __restrict__ x,
                                               unsigned short* __restrict__ xTn,
                                               float* __restrict__ score){
  const int n0 = blockIdx.x * 8, b = blockIdx.y;
  __shared__ float xl[8 * 32 * 25];
  const float* src = x + ((size_t)b * NB + n0) * DB;
  #pragma unroll
  for (int p = 0; p < 24; ++p){
    int i = p * 256 + threadIdx.x;       // 6144 floats
    int n = i / 768, rem = i % 768, f = rem / 24, t = rem % 24;
    xl[(n * 32 + f) * 25 + t] = src[i];
  }
  __syncthreads();
  #pragma unroll
  for (int nn = 0; nn < 8; ++nn){
    unsigned short* dst = xTn + ((size_t)(n0 + nn) * BTB + b * TB) * FB;
    #pragma unroll
    for (int p = 0; p < 3; ++p){
      int i2 = p * 256 + threadIdx.x;
      int t = i2 >> 5, f = i2 & 31;
      dst[t * FB + f] = f2b(xl[(nn * 32 + f) * 25 + t]);
    }
  }
  if (threadIdx.x < 192){
    const int t = threadIdx.x >> 3, u0 = (threadIdx.x & 7) * 3;
    float a0 = 0.f, a1 = 0.f, a2 = 0.f;
    for (int m = 0; m < 256; ++m){
      const float xt = xl[m * 25 + t];
      a0 = fmaf(xt, xl[m * 25 + u0 + 0], a0);
      a1 = fmaf(xt, xl[m * 25 + u0 + 1], a1);
      a2 = fmaf(xt, xl[m * 25 + u0 + 2], a2);
    }
    float* sb = score + (size_t)b * 576 + t * 24 + u0;
    atomicAdd(sb + 0, a0); atomicAdd(sb + 1, a1); atomicAdd(sb + 2, a2);
  }
}

// xTA (with inline per-block Eatt recomputation — removes k_eatt launch + buffer)
__global__ __launch_bounds__(256) void k_xta2(const unsigned short* __restrict__ xTn,
                                              const float* __restrict__ score,
                                              const float* __restrict__ Ve,
                                              const float* __restrict__ be,
                                              unsigned short* __restrict__ xTAh){
  const int n0 = blockIdx.x * 8, b = blockIdx.y;
  __shared__ float E[576], sg[576], Ar[576];
  __shared__ unsigned short xl[8 * 32 * 25];   // [(nn*32+f)*25 + t]
  // --- inline Eatt: softmax_rows(Ve @ sigmoid(score[b]) + be) ---
  for (int i = threadIdx.x; i < 576; i += 256) sg[i] = sigm(score[(size_t)b * 576 + i]);
  __syncthreads();
  for (int i = threadIdx.x; i < 576; i += 256){
    int t = i / 24, v = i % 24;
    float s = 0.f;
    #pragma unroll
    for (int u = 0; u < 24; ++u) s = fmaf(Ve[t*24+u], sg[u*24+v], s);
    Ar[i] = s + be[i];
  }
  __syncthreads();
  if (threadIdx.x < 24){
    const int t = threadIdx.x;
    float mx = -1e30f;
    #pragma unroll
    for (int v = 0; v < 24; ++v) mx = fmaxf(mx, Ar[t*24+v]);
    float e[24]; float sum = 0.f;
    #pragma unroll
    for (int v = 0; v < 24; ++v){ e[v] = expf(Ar[t*24+v] - mx); sum += e[v]; }
    const float inv = 1.f / sum;
    #pragma unroll
    for (int v = 0; v < 24; ++v) E[t*24 + v] = e[v] * inv;
  }
  // --- stage xTn tile ---
  #pragma unroll
  for (int p = 0; p < 12; ++p){
    int i = p * 256 + threadIdx.x;             // 3072 uints
    int nn = i / 384, within = i % 384;
    unsigned int v = *(const unsigned int*)(xTn + ((size_t)(n0 + nn) * BTB + b * TB) * FB + within * 2);
    int e0 = within * 2, t0 = e0 >> 5, f0 = e0 & 31;
    int e1 = e0 + 1,     t1 = e1 >> 5, f1 = e1 & 31;
    xl[(nn * 32 + f0) * 25 + t0] = (unsigned short)v;
    xl[(nn * 32 + f1) * 25 + t1] = (unsigned short)(v >> 16);
  }
  __syncthreads();
  const int r = threadIdx.x;                   // row = nn*32+f
  float in[TB], o[TB];
  #pragma unroll
  for (int u = 0; u < TB; ++u) in[u] = b2f(xl[r * 25 + u]);
  #pragma unroll
  for (int v = 0; v < TB; ++v) o[v] = 0.f;
  #pragma unroll
  for (int u = 0; u < TB; ++u){
    const float xv = in[u];
    #pragma unroll
    for (int v = 0; v < TB; ++v) o[v] = fmaf(xv, E[u*24+v], o[v]);
  }
  unsigned int pk[12];
  #pragma unroll
  for (int q = 0; q < 12; ++q)
    pk[q] = (unsigned int)f2b(o[2*q]) | ((unsigned int)f2b(o[2*q+1]) << 16);
  uint4* op = (uint4*)(xTAh + ((size_t)b * MB + n0 * 32 + r) * TB);
  op[0] = make_uint4(pk[0], pk[1], pk[2], pk[3]);
  op[1] = make_uint4(pk[4], pk[5], pk[6], pk[7]);
  op[2] = make_uint4(pk[8], pk[9], pk[10], pk[11]);
}

// transpose per batch: (1024 x 768) -> (768 x 1024), bf16
__global__ __launch_bounds__(256) void k_tr(const unsigned short* __restrict__ in,
                                            unsigned short* __restrict__ out){
  const int dt = blockIdx.x, nt = blockIdx.y, b = blockIdx.z;
  __shared__ unsigned short ts[64 * 66];
  const unsigned short* ib = in + (size_t)b * (NB * DB) + (size_t)(nt * 64) * DB + dt * 64;
  #pragma unroll
  for (int p = 0; p < 8; ++p){
    int fl = p * 256 + threadIdx.x;
    int rr = fl >> 5, cc = (fl & 31) * 2;
    unsigned int v = *(const unsigned int*)(ib + (size_t)rr * DB + cc);
    ts[rr * 66 + cc] = (unsigned short)v;
    ts[rr * 66 + cc + 1] = (unsigned short)(v >> 16);
  }
  __syncthreads();
  unsigned short* ob = out + (size_t)b * (NB * DB) + (size_t)(dt * 64) * NB + nt * 64;
  #pragma unroll
  for (int p = 0; p < 16; ++p){
    int fl = p * 256 + threadIdx.x;
    int dd = fl >> 6, nn = fl & 63;
    ob[(size_t)dd * NB + nn] = ts[nn * 66 + dd];
  }
}

// ---------------- bf16 MFMA GEMM: C[i,j] = sum_k A[i,k]*B[j,k] ----------------
// Single-buffered 32 KB LDS, 128x128 tile (R10 best config). T2 swizzle + XCD affinity.
template<int EPI>
__global__ __launch_bounds__(256, 3) void k_mgemm(const unsigned short* __restrict__ A,
                                                  const unsigned short* __restrict__ B,
                                                  unsigned short* __restrict__ C,
                                                  int lda, int ldb, int ldc, int Kk, int nbx,
                                                  long sA, long sB, long sC){
  __shared__ unsigned short As[8192];
  __shared__ unsigned short Bs[8192];
  const int d = blockIdx.x;
  const int bz = d & 7;            // XCD (round-robin heuristic) == batch
  const int rr = d >> 3;
  const int bx = rr % nbx, by = rr / nbx;
  A += (size_t)bz * sA; B += (size_t)bz * sB; C += (size_t)bz * sC;
  const int i0 = by * 128, j0 = bx * 128;
  const int tid = threadIdx.x, wave = tid >> 6, lane = tid & 63;
  const int fr = lane & 15, rowb = (lane >> 4) * 4;
  const int wr = (wave >> 1) * 64, wc = (wave & 1) * 64;
  const int srow = tid >> 3;
  const int sko = (((lane & 7) ^ (lane >> 3)) * 8);
  f32x4 acc[4][4];
  #pragma unroll
  for (int m = 0; m < 4; ++m)
    #pragma unroll
    for (int n = 0; n < 4; ++n) acc[m][n] = 0.f;

  for (int k0 = 0; k0 < Kk; k0 += 64){
    #pragma unroll
    for (int it = 0; it < 4; ++it){
      const int r = it * 32 + srow;
      gload16(A + (size_t)(i0 + r) * lda + k0 + sko, &As[(it*4 + wave) * 512]);
      gload16(B + (size_t)(j0 + r) * ldb + k0 + sko, &Bs[(it*4 + wave) * 512]);
    }
    asm volatile("s_waitcnt vmcnt(0)" ::: "memory");
    __syncthreads();
    #pragma unroll
    for (int kk = 0; kk < 2; ++kk){
      const int ch = kk * 4 + (lane >> 4);
      const int cs = (ch ^ (fr & 7)) * 8;
      sh8 af[4], bfr[4];
      #pragma unroll
      for (int m = 0; m < 4; ++m)
        af[m] = *(const sh8*)&As[(wr + m*16 + fr) * 64 + cs];
      #pragma unroll
      for (int n = 0; n < 4; ++n)
        bfr[n] = *(const sh8*)&Bs[(wc + n*16 + fr) * 64 + cs];
      #pragma unroll
      for (int m = 0; m < 4; ++m)
        #pragma unroll
        for (int n = 0; n < 4; ++n)
          acc[m][n] = __builtin_amdgcn_mfma_f32_16x16x32_bf16(af[m], bfr[n], acc[m][n], 0, 0, 0);
    }
    __syncthreads();
  }

  #pragma unroll
  for (int m = 0; m < 4; ++m){
    const int row = i0 + wr + m*16 + rowb;
    #pragma unroll
    for (int n = 0; n < 4; ++n){
      const int colg = j0 + wc + n*16 + fr;
      #pragma unroll
      for (int r = 0; r < 4; ++r){
        float v = acc[m][n][r];
        if (EPI == 1) v = sigm(v);
        C[(size_t)(row + r) * ldc + colg] = f2b(v);
      }
    }
  }
}

// row softmax of (b2f(C2h) + bs) over last dim (1024) -> bf16 Sh
__global__ __launch_bounds__(256) void k_softmax_s(const unsigned short* __restrict__ C2h,
                                                   const float* __restrict__ bs,
                                                   unsigned short* __restrict__ Sh){
  const int blk = blockIdx.x;
  const int n = blk & 1023;
  const unsigned short* row = C2h + (size_t)blk * 1024;
  const float* bsr = bs + (size_t)n * 1024;
  const int tid = threadIdx.x;
  uint2 rv = ((const uint2*)row)[tid];
  float4 bb = ((const float4*)bsr)[tid];
  float v0 = b2f((unsigned short)rv.x)         + bb.x;
  float v1 = b2f((unsigned short)(rv.x >> 16)) + bb.y;
  float v2 = b2f((unsigned short)rv.y)         + bb.z;
  float v3 = b2f((unsigned short)(rv.y >> 16)) + bb.w;
  float mx = fmaxf(fmaxf(v0, v1), fmaxf(v2, v3));
  mx = wmax(mx);
  __shared__ float s4[4];
  __shared__ float s4b[4];
  if ((tid & 63) == 0) s4[tid >> 6] = mx;
  __syncthreads();
  mx = fmaxf(fmaxf(s4[0], s4[1]), fmaxf(s4[2], s4[3]));
  float e0 = expf(v0 - mx), e1 = expf(v1 - mx), e2 = expf(v2 - mx), e3 = expf(v3 - mx);
  float sum = wsum(e0 + e1 + e2 + e3);
  if ((tid & 63) == 0) s4b[tid >> 6] = sum;
  __syncthreads();
  sum = s4b[0] + s4b[1] + s4b[2] + s4b[3];
  const float inv = 1.f / sum;
  uint2 ov;
  ov.x = (unsigned int)f2b(e0 * inv) | ((unsigned int)f2b(e1 * inv) << 16);
  ov.y = (unsigned int)f2b(e2 * inv) | ((unsigned int)f2b(e3 * inv) << 16);
  ((uint2*)(Sh + (size_t)blk * 1024))[tid] = ov;
}

// T0n[(n*192 + b*24 + t)*32 + f] = xSA_h[b, n, f*24+t]   (node-major layout)
__global__ __launch_bounds__(256) void k_t0n(const unsigned short* __restrict__ xSAh,
                                             unsigned short* __restrict__ T0n){
  const int n0 = blockIdx.x * 8, b = blockIdx.y;
  __shared__ unsigned short s[8 * 32 * 25];
  const unsigned int* src = (const unsigned int*)(xSAh + ((size_t)b * NB + n0) * DB);
  #pragma unroll
  for (int p = 0; p < 12; ++p){
    int i = p * 256 + threadIdx.x;
    unsigned int v = src[i];
    int d0 = (i * 2) % DB, nn = (i * 2) / DB;
    int f0 = d0 / 24, t0 = d0 % 24;
    int d1 = d0 + 1, f1 = d1 / 24, t1 = d1 % 24;
    s[(nn * 32 + f0) * 25 + t0] = (unsigned short)v;
    s[(nn * 32 + f1) * 25 + t1] = (unsigned short)(v >> 16);
  }
  __syncthreads();
  #pragma unroll
  for (int nn = 0; nn < 8; ++nn){
    unsigned short* dst = T0n + ((size_t)(n0 + nn) * BTB + b * TB) * FB;
    #pragma unroll
    for (int p = 0; p < 3; ++p){
      int i2 = p * 256 + threadIdx.x;
      int t = i2 >> 5, f = i2 & 31;
      dst[t * FB + f] = s[(nn * 32 + f) * 25 + t];
    }
  }
}

// ---------------- fused graph build: deg + scan + fill, one block (LDS-only state) ----------------
__global__ __launch_bounds__(1024) void k_graph(const int* __restrict__ ei,
                                                const float* __restrict__ ew,
                                                int* __restrict__ ptr,
                                                int* __restrict__ cidx,
                                                float* __restrict__ normv){
  __shared__ float degs[1024];
  __shared__ int cnts[1024];
  __shared__ int base[1024];
  __shared__ int sd[1024];
  const int i = threadIdx.x;
  degs[i] = 0.f; cnts[i] = 0;
  __syncthreads();
  #pragma unroll
  for (int p = 0; p < 16; ++p){
    int e = p * 1024 + i;
    int r = ei[e], c = ei[EB + e];
    float w = (r == c) ? 0.f : ew[e];
    atomicAdd(&degs[r], w);
    atomicAdd(&cnts[c], 1);
  }
  __syncthreads();
  int c = cnts[i];
  sd[i] = c;
  __syncthreads();
  int v = c;
  for (int s = 1; s < 1024; s <<= 1){
    int t = (i >= s) ? sd[i - s] : 0;
    __syncthreads();
    v += t; sd[i] = v;
    __syncthreads();
  }
  ptr[i + 1] = v;
  base[i] = v - c;
  if (i == 0) ptr[0] = 0;
  __syncthreads();
  #pragma unroll
  for (int p = 0; p < 16; ++p){
    int e = p * 1024 + i;
    int r = ei[e], cc = ei[EB + e];
    float w = (r == cc) ? 0.f : ew[e];
    float dr = degs[r], dc = degs[cc];
    float ir = dr > 0.f ? rsqrtf(dr) : 0.f;
    float ic = dc > 0.f ? rsqrtf(dc) : 0.f;
    normv[e] = -ir * w * ic;
    int pos = atomicAdd(&base[cc], 1);
    cidx[pos] = e;
  }
}

// ---------------- streaming SpMM, XCD-affine slices + 8-deep gather ILP ----------------
#define ACC8W(vv, wv) { \
  acc[0] = fmaf(wv, b2f((unsigned short)(vv).x), acc[0]); \
  acc[1] = fmaf(wv, b2f((unsigned short)((vv).x >> 16)), acc[1]); \
  acc[2] = fmaf(wv, b2f((unsigned short)(vv).y), acc[2]); \
  acc[3] = fmaf(wv, b2f((unsigned short)((vv).y >> 16)), acc[3]); \
  acc[4] = fmaf(wv, b2f((unsigned short)(vv).z), acc[4]); \
  acc[5] = fmaf(wv, b2f((unsigned short)((vv).z >> 16)), acc[5]); \
  acc[6] = fmaf(wv, b2f((unsigned short)(vv).w), acc[6]); \
  acc[7] = fmaf(wv, b2f((unsigned short)((vv).w >> 16)), acc[7]); }

__global__ __launch_bounds__(192) void k_spmm(const unsigned short* __restrict__ z,
                                              const float* __restrict__ normv,
                                              const int* __restrict__ cidx,
                                              const int* __restrict__ ei,
                                              const int* __restrict__ ptr,
                                              const unsigned short* __restrict__ sub,
                                              float scale,
                                              unsigned short* __restrict__ outz){
  const int s = blockIdx.x & 3;
  const int c = blockIdx.x >> 2;
  const int off = s * 1536 + threadIdx.x * 8;   // 8 bf16 (16 B) per thread
  const int j0 = ptr[c], j1 = ptr[c + 1];
  __shared__ int rs[192];
  __shared__ float ws[192];
  float acc[8] = {0.f, 0.f, 0.f, 0.f, 0.f, 0.f, 0.f, 0.f};
  for (int jb = j0; jb < j1; jb += 192){
    const int cnt = min(192, j1 - jb);
    __syncthreads();
    if (threadIdx.x < cnt){
      int e = cidx[jb + threadIdx.x];
      rs[threadIdx.x] = ei[e];
      ws[threadIdx.x] = normv[e];
    }
    __syncthreads();
    int j = 0;
    for (; j + 8 <= cnt; j += 8){
      uint4 v0 = *(const uint4*)(z + (size_t)rs[j+0] * WSP + off);
      uint4 v1 = *(const uint4*)(z + (size_t)rs[j+1] * WSP + off);
      uint4 v2 = *(const uint4*)(z + (size_t)rs[j+2] * WSP + off);
      uint4 v3 = *(const uint4*)(z + (size_t)rs[j+3] * WSP + off);
      uint4 v4 = *(const uint4*)(z + (size_t)rs[j+4] * WSP + off);
      uint4 v5 = *(const uint4*)(z + (size_t)rs[j+5] * WSP + off);
      uint4 v6 = *(const uint4*)(z + (size_t)rs[j+6] * WSP + off);
      uint4 v7 = *(const uint4*)(z + (size_t)rs[j+7] * WSP + off);
      float w0 = ws[j+0], w1 = ws[j+1], w2 = ws[j+2], w3 = ws[j+3];
      float w4 = ws[j+4], w5 = ws[j+5], w6 = ws[j+6], w7 = ws[j+7];
      ACC8W(v0, w0) ACC8W(v1, w1) ACC8W(v2, w2) ACC8W(v3, w3)
      ACC8W(v4, w4) ACC8W(v5, w5) ACC8W(v6, w6) ACC8W(v7, w7)
    }
    if (j + 4 <= cnt){
      uint4 v0 = *(const uint4*)(z + (size_t)rs[j+0] * WSP + off);
      uint4 v1 = *(const uint4*)(z + (size_t)rs[j+1] * WSP + off);
      uint4 v2 = *(const uint4*)(z + (size_t)rs[j+2] * WSP + off);
      uint4 v3 = *(const uint4*)(z + (size_t)rs[j+3] * WSP + off);
      float w0 = ws[j+0], w1 = ws[j+1], w2 = ws[j+2], w3 = ws[j+3];
      ACC8W(v0, w0) ACC8W(v1, w1) ACC8W(v2, w2) ACC8W(v3, w3)
      j += 4;
    }
    for (; j < cnt; ++j){
      const uint4 v = *(const uint4*)(z + (size_t)rs[j] * WSP + off);
      const float w = ws[j];
      ACC8W(v, w)
    }
  }
  float sv[8] = {0.f, 0.f, 0.f, 0.f, 0.f, 0.f, 0.f, 0.f};
  if (sub){
    const uint4 s0 = *(const uint4*)(sub + (size_t)c * WSP + off);
    sv[0]=b2f((unsigned short)s0.x); sv[1]=b2f((unsigned short)(s0.x>>16));
    sv[2]=b2f((unsigned short)s0.y); sv[3]=b2f((unsigned short)(s0.y>>16));
    sv[4]=b2f((unsigned short)s0.z); sv[5]=b2f((unsigned short)(s0.z>>16));
    sv[6]=b2f((unsigned short)s0.w); sv[7]=b2f((unsigned short)(s0.w>>16));
  }
  unsigned int pk[4];
  #pragma unroll
  for (int q = 0; q < 4; ++q){
    float a = scale * acc[2*q]     - sv[2*q];
    float b = scale * acc[2*q + 1] - sv[2*q + 1];
    pk[q] = (unsigned int)f2b(a) | ((unsigned int)f2b(b) << 16);
  }
  *(uint4*)(outz + (size_t)c * WSP + off) = make_uint4(pk[0], pk[1], pk[2], pk[3]);
}

// ---------------- fused final GEMM + relayout: out[b,n,g,t] = relu(...) ----------------
__global__ __launch_bounds__(256) void k_fgemm(const unsigned short* __restrict__ T0n,
                                               const unsigned short* __restrict__ T1n,
                                               const unsigned short* __restrict__ T2n,
                                               const unsigned short* __restrict__ xTn,
                                               const unsigned short* __restrict__ Wh,
                                               const float* __restrict__ bsum,
                                               float* __restrict__ out){
  __shared__ unsigned short As[16384];
  __shared__ unsigned short Ws[8192];
  const int m0 = blockIdx.x * 128;
  const int tid = threadIdx.x, wave = tid >> 6, lane = tid & 63;
  const int fr = lane & 15, rowb = (lane >> 4) * 4;
  const int wr = (wave >> 1) * 64, wc = (wave & 1) * 32;
  #pragma unroll
  for (int it = 0; it < 8; ++it){
    const int row = it * 16 + wave * 4 + (lane >> 4);
    const int g = (lane & 15) ^ (row & 7);
    const int ss = g >> 2, off = (g & 3) * 8;
    const unsigned short* bp = (ss == 0) ? T0n : (ss == 1) ? T1n : (ss == 2) ? T2n : xTn;
    gload16(bp + (size_t)(m0 + row) * FB + off, &As[(it*4 + wave) * 512]);
  }
  #pragma unroll
  for (int it = 0; it < 4; ++it){
    const int row = it * 16 + wave * 4 + (lane >> 4);
    const int g = (lane & 15) ^ (row & 7);
    gload16(Wh + (size_t)row * 128 + g * 8, &Ws[(it*4 + wave) * 512]);
  }
  __syncthreads();
  f32x4 acc[4][2];
  #pragma unroll
  for (int m = 0; m < 4; ++m){ acc[m][0] = 0.f; acc[m][1] = 0.f; }
  #pragma unroll
  for (int kk = 0; kk < 4; ++kk){
    const int ch = kk * 4 + (lane >> 4);
    const int cs = (ch ^ (fr & 7)) * 8;
    sh8 af[4], bf2[2];
    #pragma unroll
    for (int m = 0; m < 4; ++m)
      af[m] = *(const sh8*)&As[(wr + m*16 + fr) * 128 + cs];
    #pragma unroll
    for (int n = 0; n < 2; ++n)
      bf2[n] = *(const sh8*)&Ws[(wc + n*16 + fr) * 128 + cs];
    #pragma unroll
    for (int m = 0; m < 4; ++m)
      #pragma unroll
      for (int n = 0; n < 2; ++n)
        acc[m][n] = __builtin_amdgcn_mfma_f32_16x16x32_bf16(af[m], bf2[n], acc[m][n], 0, 0, 0);
  }
  #pragma unroll
  for (int m = 0; m < 4; ++m){
    const int row4 = m0 + wr + m*16 + rowb;
    const int nn = row4 / 192;
    const int rem = row4 - nn * 192;
    const int b = rem / 24;
    const int t0 = rem - b * 24;
    #pragma unroll
    for (int n = 0; n < 2; ++n){
      const int g = wc + n*16 + fr;
      const float bv = bsum[g];
      float4 v;
      v.x = fmaxf(acc[m][n][0] + bv, 0.f);
      v.y = fmaxf(acc[m][n][1] + bv, 0.f);
      v.z = fmaxf(acc[m][n][2] + bv, 0.f);
      v.w = fmaxf(acc[m][n][3] + bv, 0.f);
      *(float4*)(out + (((size_t)b * NB + nn) * GB + g) * TB + t0) = v;
    }
  }
}

// ---------------- fused constants: Wcat + score-zero (block 0), Vs->bf16 (blocks 1..1024) ----------------
__global__ __launch_bounds__(256) void k_const(const float* __restrict__ Vs,
                                               const float* __restrict__ cW,
                                               const float* __restrict__ cB,
                                               const float* __restrict__ rW,
                                               const float* __restrict__ rB,
                                               unsigned short* __restrict__ Vsh,
                                               unsigned short* __restrict__ Wh,
                                               float* __restrict__ bsum,
                                               float* __restrict__ score){
  if (blockIdx.x == 0){
    for (int i = threadIdx.x; i < 8192; i += 256){
      int g = i >> 7, k = i & 127;
      int s = k >> 5, f = k & 31;
      float v = (s < 3) ? cW[(s * 32 + f) * 64 + g] : rW[g * 32 + f];
      Wh[i] = f2b(v);
    }
    if (threadIdx.x < 64) bsum[threadIdx.x] = cB[threadIdx.x] + rB[threadIdx.x];
    for (int i = threadIdx.x; i < 4608; i += 256) score[i] = 0.f;
  } else {
    int i = ((blockIdx.x - 1) * 256 + threadIdx.x) * 4;
    float4 v = *(const float4*)(Vs + i);
    unsigned short* o = Vsh + i;
    o[0] = f2b(v.x); o[1] = f2b(v.y); o[2] = f2b(v.z); o[3] = f2b(v.w);
  }
}

extern "C" void kernel_launch(void* const* d_in, const int* in_sizes, int n_in,
                              void* d_out, int out_size, void* d_ws, size_t ws_size,
                              hipStream_t stream){
  const float* x  = (const float*)d_in[0];
  const int*   ei = (const int*)d_in[1];
  const float* ew = (const float*)d_in[2];
  const float* Ve = (const float*)d_in[3];
  const float* be = (const float*)d_in[4];
  const float* Vs = (const float*)d_in[5];
  const float* bs = (const float*)d_in[6];
  const float* cW = (const float*)d_in[7];
  const float* cB = (const float*)d_in[8];
  const float* rW = (const float*)d_in[9];
  const float* rB = (const float*)d_in[10];
  float* out = (float*)d_out;

  char* W = (char*)d_ws;
  unsigned short* sigh  = (unsigned short*)(W + 0);          // 16 MB: sig -> later Sh
  unsigned short* Sh    = sigh;
  unsigned short* xTAh  = (unsigned short*)(W + 16777216);   // 12 MB: xTA bf16 -> later T0n
  unsigned short* T0n   = xTAh;
  unsigned short* xTAhT = (unsigned short*)(W + 29360128);   // 12 MB: xTA^T -> later T1n
  unsigned short* T1n   = xTAhT;
  unsigned short* xTn   = (unsigned short*)(W + 41943040);   // 12 MB: x node-major bf16
  unsigned short* xSAh  = (unsigned short*)(W + 54525952);   // 12 MB: xSA bf16 -> later T2n
  unsigned short* T2n   = xSAh;
  unsigned short* C2h   = (unsigned short*)(W + 67108864);   // 16 MB logits
  unsigned short* Vsh   = (unsigned short*)(W + 83886080);   // 2 MB
  unsigned short* Wh    = (unsigned short*)(W + 92274688);   // 16 KB
  float* bsum  = (float*)(W + 92291072);
  float* score = (float*)(W + 92291328);
  float* normv = (float*)(W + 92328192);
  int*   ptr   = (int*)(W + 92401920);
  int*   cidx  = (int*)(W + 92410368);

  // constants + score zeroing (fused), graph build (fused single block)
  k_const<<<1025, 256, 0, stream>>>(Vs, cW, cB, rW, rB, Vsh, Wh, bsum, score);
  k_graph<<<1, 1024, 0, stream>>>(ei, ew, ptr, cidx, normv);

  // fused pass 1: single read of x -> xTn + Gram score
  k_pass1<<<dim3(128, 8), 256, 0, stream>>>(x, xTn, score);
  k_xta2<<<dim3(128, 8), 256, 0, stream>>>(xTn, score, Ve, be, xTAh);
  k_tr<<<dim3(12, 16, 8), 256, 0, stream>>>(xTAh, xTAhT);

  // spatial attention: three bf16 MFMA GEMMs (single-buffer 128x128, swizzle, XCD affinity)
  k_mgemm<1><<<512, 256, 0, stream>>>(xTAh, xTAh, sigh, DB, DB, NB, DB, 8,
                                      (long)NB*DB, (long)NB*DB, (long)NB*NB);
  k_mgemm<2><<<512, 256, 0, stream>>>(Vsh, sigh, C2h, NB, NB, NB, NB, 8,
                                      0L, (long)NB*NB, (long)NB*NB);
  k_softmax_s<<<8192, 256, 0, stream>>>(C2h, bs, Sh);
  k_mgemm<2><<<384, 256, 0, stream>>>(Sh, xTAhT, xSAh, NB, NB, DB, NB, 6,
                                      (long)NB*NB, (long)NB*DB, (long)NB*DB);

  // ChebConv: node-major layout + 2 XCD-affine ILP SpMMs
  k_t0n<<<dim3(128, 8), 256, 0, stream>>>(xSAh, T0n);
  k_spmm<<<4096, 192, 0, stream>>>(T0n, normv, cidx, ei, ptr, nullptr, 1.f, T1n);
  k_spmm<<<4096, 192, 0, stream>>>(T1n, normv, cidx, ei, ptr, T0n, 2.f, T2n);

  // fused Cheb matmuls + residual + bias + relu + relayout (direct f32 out)
  k_fgemm<<<1536, 256, 0, stream>>>(T0n, T1n, T2n, xTn, Wh, bsum, out);
}

// Round 13
// 215.367 us; speedup vs baseline: 1.0687x; 1.0687x over previous
//
#include <hip/hip_runtime.h>
#include <math.h>

// Problem constants
#define NB 1024     // nodes
#define FB 32       // F_IN
#define TB 24       // T
#define GB 64       // F_OUT
#define BB 8        // batch
#define EB 16384    // edges
#define MB 32768    // N*F
#define DB 768      // F*T
#define BTB 192     // B*T
#define WSP 6144    // BT*F width of node-major T matrices

typedef __attribute__((ext_vector_type(8))) short sh8;     // 8 bf16 (4 VGPRs)
typedef __attribute__((ext_vector_type(4))) float f32x4;   // MFMA accumulator

__device__ __forceinline__ float wsum(float v){
  #pragma unroll
  for (int o = 32; o; o >>= 1) v += __shfl_down(v, o);
  return v;
}
__device__ __forceinline__ float wmax(float v){
  #pragma unroll
  for (int o = 32; o; o >>= 1) v = fmaxf(v, __shfl_down(v, o));
  return v;
}
__device__ __forceinline__ float sigm(float v){ return 1.f / (1.f + expf(-v)); }
__device__ __forceinline__ float b2f(unsigned short u){ unsigned int t = ((unsigned int)u) << 16; return __uint_as_float(t); }
__device__ __forceinline__ unsigned short f2b(float f){
  unsigned int u = __float_as_uint(f);
  u += 0x7fffu + ((u >> 16) & 1u);
  return (unsigned short)(u >> 16);
}
__device__ __forceinline__ void gload16(const void* g, void* l){
  typedef const __attribute__((address_space(1))) unsigned int* gp_t;
  typedef __attribute__((address_space(3))) unsigned int* lp_t;
  __builtin_amdgcn_global_load_lds((gp_t)g, (lp_t)l, 16, 0, 0);
}

// ---------------- fused pass 1: x -> xTn (node-major bf16) + Gram partials ----------------
__global__ __launch_bounds__(256) void k_pass1(const float* __restrict__ x,
                                               unsigned short* __restrict__ xTn,
                                               float* __restrict__ score){
  const int n0 = blockIdx.x * 8, b = blockIdx.y;
  __shared__ float xl[8 * 32 * 25];
  const float* src = x + ((size_t)b * NB + n0) * DB;
  #pragma unroll
  for (int p = 0; p < 24; ++p){
    int i = p * 256 + threadIdx.x;       // 6144 floats
    int n = i / 768, rem = i % 768, f = rem / 24, t = rem % 24;
    xl[(n * 32 + f) * 25 + t] = src[i];
  }
  __syncthreads();
  #pragma unroll
  for (int nn = 0; nn < 8; ++nn){
    unsigned short* dst = xTn + ((size_t)(n0 + nn) * BTB + b * TB) * FB;
    #pragma unroll
    for (int p = 0; p < 3; ++p){
      int i2 = p * 256 + threadIdx.x;
      int t = i2 >> 5, f = i2 & 31;
      dst[t * FB + f] = f2b(xl[(nn * 32 + f) * 25 + t]);
    }
  }
  if (threadIdx.x < 192){
    const int t = threadIdx.x >> 3, u0 = (threadIdx.x & 7) * 3;
    float a0 = 0.f, a1 = 0.f, a2 = 0.f;
    for (int m = 0; m < 256; ++m){
      const float xt = xl[m * 25 + t];
      a0 = fmaf(xt, xl[m * 25 + u0 + 0], a0);
      a1 = fmaf(xt, xl[m * 25 + u0 + 1], a1);
      a2 = fmaf(xt, xl[m * 25 + u0 + 2], a2);
    }
    float* sb = score + (size_t)b * 576 + t * 24 + u0;
    atomicAdd(sb + 0, a0); atomicAdd(sb + 1, a1); atomicAdd(sb + 2, a2);
  }
}

// xTA (with inline per-block Eatt recomputation — removes k_eatt launch + buffer)
__global__ __launch_bounds__(256) void k_xta2(const unsigned short* __restrict__ xTn,
                                              const float* __restrict__ score,
                                              const float* __restrict__ Ve,
                                              const float* __restrict__ be,
                                              unsigned short* __restrict__ xTAh){
  const int n0 = blockIdx.x * 8, b = blockIdx.y;
  __shared__ float E[576], sg[576], Ar[576];
  __shared__ unsigned short xl[8 * 32 * 25];   // [(nn*32+f)*25 + t]
  for (int i = threadIdx.x; i < 576; i += 256) sg[i] = sigm(score[(size_t)b * 576 + i]);
  __syncthreads();
  for (int i = threadIdx.x; i < 576; i += 256){
    int t = i / 24, v = i % 24;
    float s = 0.f;
    #pragma unroll
    for (int u = 0; u < 24; ++u) s = fmaf(Ve[t*24+u], sg[u*24+v], s);
    Ar[i] = s + be[i];
  }
  __syncthreads();
  if (threadIdx.x < 24){
    const int t = threadIdx.x;
    float mx = -1e30f;
    #pragma unroll
    for (int v = 0; v < 24; ++v) mx = fmaxf(mx, Ar[t*24+v]);
    float e[24]; float sum = 0.f;
    #pragma unroll
    for (int v = 0; v < 24; ++v){ e[v] = expf(Ar[t*24+v] - mx); sum += e[v]; }
    const float inv = 1.f / sum;
    #pragma unroll
    for (int v = 0; v < 24; ++v) E[t*24 + v] = e[v] * inv;
  }
  #pragma unroll
  for (int p = 0; p < 12; ++p){
    int i = p * 256 + threadIdx.x;             // 3072 uints
    int nn = i / 384, within = i % 384;
    unsigned int v = *(const unsigned int*)(xTn + ((size_t)(n0 + nn) * BTB + b * TB) * FB + within * 2);
    int e0 = within * 2, t0 = e0 >> 5, f0 = e0 & 31;
    int e1 = e0 + 1,     t1 = e1 >> 5, f1 = e1 & 31;
    xl[(nn * 32 + f0) * 25 + t0] = (unsigned short)v;
    xl[(nn * 32 + f1) * 25 + t1] = (unsigned short)(v >> 16);
  }
  __syncthreads();
  const int r = threadIdx.x;                   // row = nn*32+f
  float in[TB], o[TB];
  #pragma unroll
  for (int u = 0; u < TB; ++u) in[u] = b2f(xl[r * 25 + u]);
  #pragma unroll
  for (int v = 0; v < TB; ++v) o[v] = 0.f;
  #pragma unroll
  for (int u = 0; u < TB; ++u){
    const float xv = in[u];
    #pragma unroll
    for (int v = 0; v < TB; ++v) o[v] = fmaf(xv, E[u*24+v], o[v]);
  }
  unsigned int pk[12];
  #pragma unroll
  for (int q = 0; q < 12; ++q)
    pk[q] = (unsigned int)f2b(o[2*q]) | ((unsigned int)f2b(o[2*q+1]) << 16);
  uint4* op = (uint4*)(xTAh + ((size_t)b * MB + n0 * 32 + r) * TB);
  op[0] = make_uint4(pk[0], pk[1], pk[2], pk[3]);
  op[1] = make_uint4(pk[4], pk[5], pk[6], pk[7]);
  op[2] = make_uint4(pk[8], pk[9], pk[10], pk[11]);
}

// transpose per batch: (1024 x 768) -> (768 x 1024), bf16
__global__ __launch_bounds__(256) void k_tr(const unsigned short* __restrict__ in,
                                            unsigned short* __restrict__ out){
  const int dt = blockIdx.x, nt = blockIdx.y, b = blockIdx.z;
  __shared__ unsigned short ts[64 * 66];
  const unsigned short* ib = in + (size_t)b * (NB * DB) + (size_t)(nt * 64) * DB + dt * 64;
  #pragma unroll
  for (int p = 0; p < 8; ++p){
    int fl = p * 256 + threadIdx.x;
    int rr = fl >> 5, cc = (fl & 31) * 2;
    unsigned int v = *(const unsigned int*)(ib + (size_t)rr * DB + cc);
    ts[rr * 66 + cc] = (unsigned short)v;
    ts[rr * 66 + cc + 1] = (unsigned short)(v >> 16);
  }
  __syncthreads();
  unsigned short* ob = out + (size_t)b * (NB * DB) + (size_t)(dt * 64) * NB + nt * 64;
  #pragma unroll
  for (int p = 0; p < 16; ++p){
    int fl = p * 256 + threadIdx.x;
    int dd = fl >> 6, nn = fl & 63;
    ob[(size_t)dd * NB + nn] = ts[nn * 66 + dd];
  }
}

// ---------------- bf16 MFMA GEMM: C[i,j] = sum_k A[i,k]*B[j,k] ----------------
// Single-buffered 32 KB LDS, 128x128 tile (R10 best config). T2 swizzle + XCD affinity.
template<int EPI>
__global__ __launch_bounds__(256, 3) void k_mgemm(const unsigned short* __restrict__ A,
                                                  const unsigned short* __restrict__ B,
                                                  unsigned short* __restrict__ C,
                                                  int lda, int ldb, int ldc, int Kk, int nbx,
                                                  long sA, long sB, long sC){
  __shared__ unsigned short As[8192];
  __shared__ unsigned short Bs[8192];
  const int d = blockIdx.x;
  const int bz = d & 7;            // XCD (round-robin heuristic) == batch
  const int rr = d >> 3;
  const int bx = rr % nbx, by = rr / nbx;
  A += (size_t)bz * sA; B += (size_t)bz * sB; C += (size_t)bz * sC;
  const int i0 = by * 128, j0 = bx * 128;
  const int tid = threadIdx.x, wave = tid >> 6, lane = tid & 63;
  const int fr = lane & 15, rowb = (lane >> 4) * 4;
  const int wr = (wave >> 1) * 64, wc = (wave & 1) * 64;
  const int srow = tid >> 3;
  const int sko = (((lane & 7) ^ (lane >> 3)) * 8);
  f32x4 acc[4][4];
  #pragma unroll
  for (int m = 0; m < 4; ++m)
    #pragma unroll
    for (int n = 0; n < 4; ++n) acc[m][n] = 0.f;

  for (int k0 = 0; k0 < Kk; k0 += 64){
    #pragma unroll
    for (int it = 0; it < 4; ++it){
      const int r = it * 32 + srow;
      gload16(A + (size_t)(i0 + r) * lda + k0 + sko, &As[(it*4 + wave) * 512]);
      gload16(B + (size_t)(j0 + r) * ldb + k0 + sko, &Bs[(it*4 + wave) * 512]);
    }
    asm volatile("s_waitcnt vmcnt(0)" ::: "memory");
    __syncthreads();
    #pragma unroll
    for (int kk = 0; kk < 2; ++kk){
      const int ch = kk * 4 + (lane >> 4);
      const int cs = (ch ^ (fr & 7)) * 8;
      sh8 af[4], bfr[4];
      #pragma unroll
      for (int m = 0; m < 4; ++m)
        af[m] = *(const sh8*)&As[(wr + m*16 + fr) * 64 + cs];
      #pragma unroll
      for (int n = 0; n < 4; ++n)
        bfr[n] = *(const sh8*)&Bs[(wc + n*16 + fr) * 64 + cs];
      #pragma unroll
      for (int m = 0; m < 4; ++m)
        #pragma unroll
        for (int n = 0; n < 4; ++n)
          acc[m][n] = __builtin_amdgcn_mfma_f32_16x16x32_bf16(af[m], bfr[n], acc[m][n], 0, 0, 0);
    }
    __syncthreads();
  }

  #pragma unroll
  for (int m = 0; m < 4; ++m){
    const int row = i0 + wr + m*16 + rowb;
    #pragma unroll
    for (int n = 0; n < 4; ++n){
      const int colg = j0 + wc + n*16 + fr;
      #pragma unroll
      for (int r = 0; r < 4; ++r){
        float v = acc[m][n][r];
        if (EPI == 1) v = sigm(v);
        C[(size_t)(row + r) * ldc + colg] = f2b(v);
      }
    }
  }
}

// row softmax of (b2f(C2h) + bs) over last dim (1024) -> bf16 Sh
__global__ __launch_bounds__(256) void k_softmax_s(const unsigned short* __restrict__ C2h,
                                                   const float* __restrict__ bs,
                                                   unsigned short* __restrict__ Sh){
  const int blk = blockIdx.x;
  const int n = blk & 1023;
  const unsigned short* row = C2h + (size_t)blk * 1024;
  const float* bsr = bs + (size_t)n * 1024;
  const int tid = threadIdx.x;
  uint2 rv = ((const uint2*)row)[tid];
  float4 bb = ((const float4*)bsr)[tid];
  float v0 = b2f((unsigned short)rv.x)         + bb.x;
  float v1 = b2f((unsigned short)(rv.x >> 16)) + bb.y;
  float v2 = b2f((unsigned short)rv.y)         + bb.z;
  float v3 = b2f((unsigned short)(rv.y >> 16)) + bb.w;
  float mx = fmaxf(fmaxf(v0, v1), fmaxf(v2, v3));
  mx = wmax(mx);
  __shared__ float s4[4];
  __shared__ float s4b[4];
  if ((tid & 63) == 0) s4[tid >> 6] = mx;
  __syncthreads();
  mx = fmaxf(fmaxf(s4[0], s4[1]), fmaxf(s4[2], s4[3]));
  float e0 = expf(v0 - mx), e1 = expf(v1 - mx), e2 = expf(v2 - mx), e3 = expf(v3 - mx);
  float sum = wsum(e0 + e1 + e2 + e3);
  if ((tid & 63) == 0) s4b[tid >> 6] = sum;
  __syncthreads();
  sum = s4b[0] + s4b[1] + s4b[2] + s4b[3];
  const float inv = 1.f / sum;
  uint2 ov;
  ov.x = (unsigned int)f2b(e0 * inv) | ((unsigned int)f2b(e1 * inv) << 16);
  ov.y = (unsigned int)f2b(e2 * inv) | ((unsigned int)f2b(e3 * inv) << 16);
  ((uint2*)(Sh + (size_t)blk * 1024))[tid] = ov;
}

// T0n[(n*192 + b*24 + t)*32 + f] = xSA_h[b, n, f*24+t]   (node-major layout)
__global__ __launch_bounds__(256) void k_t0n(const unsigned short* __restrict__ xSAh,
                                             unsigned short* __restrict__ T0n){
  const int n0 = blockIdx.x * 8, b = blockIdx.y;
  __shared__ unsigned short s[8 * 32 * 25];
  const unsigned int* src = (const unsigned int*)(xSAh + ((size_t)b * NB + n0) * DB);
  #pragma unroll
  for (int p = 0; p < 12; ++p){
    int i = p * 256 + threadIdx.x;
    unsigned int v = src[i];
    int d0 = (i * 2) % DB, nn = (i * 2) / DB;
    int f0 = d0 / 24, t0 = d0 % 24;
    int d1 = d0 + 1, f1 = d1 / 24, t1 = d1 % 24;
    s[(nn * 32 + f0) * 25 + t0] = (unsigned short)v;
    s[(nn * 32 + f1) * 25 + t1] = (unsigned short)(v >> 16);
  }
  __syncthreads();
  #pragma unroll
  for (int nn = 0; nn < 8; ++nn){
    unsigned short* dst = T0n + ((size_t)(n0 + nn) * BTB + b * TB) * FB;
    #pragma unroll
    for (int p = 0; p < 3; ++p){
      int i2 = p * 256 + threadIdx.x;
      int t = i2 >> 5, f = i2 & 31;
      dst[t * FB + f] = s[(nn * 32 + f) * 25 + t];
    }
  }
}

// ---------------- ChebConv graph machinery (parallel 3-kernel build) ----------------
__global__ __launch_bounds__(256) void k_edge_deg(const int* __restrict__ ei,
                                                  const float* __restrict__ ew,
                                                  float* __restrict__ deg,
                                                  int* __restrict__ cnt){
  int e = blockIdx.x * 256 + threadIdx.x;
  if (e >= EB) return;
  int r = ei[e], c = ei[EB + e];
  float w = (r == c) ? 0.f : ew[e];
  atomicAdd(&deg[r], w);
  atomicAdd(&cnt[c], 1);
}

__global__ __launch_bounds__(1024) void k_scan(const int* __restrict__ cnt,
                                               int* __restrict__ ptr,
                                               int* __restrict__ fill){
  __shared__ int sd[1024];
  const int i = threadIdx.x;
  int c = cnt[i];
  sd[i] = c;
  __syncthreads();
  int v = c;
  for (int s = 1; s < 1024; s <<= 1){
    int t = (i >= s) ? sd[i - s] : 0;
    __syncthreads();
    v += t; sd[i] = v;
    __syncthreads();
  }
  ptr[i + 1] = v;
  fill[i] = v - c;
  if (i == 0) ptr[0] = 0;
}

__global__ __launch_bounds__(256) void k_edge_fill(const int* __restrict__ ei,
                                                   const float* __restrict__ ew,
                                                   const float* __restrict__ deg,
                                                   int* __restrict__ fill,
                                                   int* __restrict__ cidx,
                                                   float* __restrict__ normv){
  int e = blockIdx.x * 256 + threadIdx.x;
  if (e >= EB) return;
  int r = ei[e], c = ei[EB + e];
  float w = (r == c) ? 0.f : ew[e];
  float dr = deg[r], dc = deg[c];
  float ir = dr > 0.f ? rsqrtf(dr) : 0.f;
  float ic = dc > 0.f ? rsqrtf(dc) : 0.f;
  normv[e] = -ir * w * ic;
  int pos = atomicAdd(&fill[c], 1);
  cidx[pos] = e;
}

// ---------------- streaming SpMM, XCD-affine slices + 8-deep gather ILP ----------------
#define ACC8W(vv, wv) { \
  acc[0] = fmaf(wv, b2f((unsigned short)(vv).x), acc[0]); \
  acc[1] = fmaf(wv, b2f((unsigned short)((vv).x >> 16)), acc[1]); \
  acc[2] = fmaf(wv, b2f((unsigned short)(vv).y), acc[2]); \
  acc[3] = fmaf(wv, b2f((unsigned short)((vv).y >> 16)), acc[3]); \
  acc[4] = fmaf(wv, b2f((unsigned short)(vv).z), acc[4]); \
  acc[5] = fmaf(wv, b2f((unsigned short)((vv).z >> 16)), acc[5]); \
  acc[6] = fmaf(wv, b2f((unsigned short)(vv).w), acc[6]); \
  acc[7] = fmaf(wv, b2f((unsigned short)((vv).w >> 16)), acc[7]); }

__global__ __launch_bounds__(192) void k_spmm(const unsigned short* __restrict__ z,
                                              const float* __restrict__ normv,
                                              const int* __restrict__ cidx,
                                              const int* __restrict__ ei,
                                              const int* __restrict__ ptr,
                                              const unsigned short* __restrict__ sub,
                                              float scale,
                                              unsigned short* __restrict__ outz){
  const int s = blockIdx.x & 3;
  const int c = blockIdx.x >> 2;
  const int off = s * 1536 + threadIdx.x * 8;   // 8 bf16 (16 B) per thread
  const int j0 = ptr[c], j1 = ptr[c + 1];
  __shared__ int rs[192];
  __shared__ float ws[192];
  float acc[8] = {0.f, 0.f, 0.f, 0.f, 0.f, 0.f, 0.f, 0.f};
  for (int jb = j0; jb < j1; jb += 192){
    const int cnt = min(192, j1 - jb);
    __syncthreads();
    if (threadIdx.x < cnt){
      int e = cidx[jb + threadIdx.x];
      rs[threadIdx.x] = ei[e];
      ws[threadIdx.x] = normv[e];
    }
    __syncthreads();
    int j = 0;
    for (; j + 8 <= cnt; j += 8){
      uint4 v0 = *(const uint4*)(z + (size_t)rs[j+0] * WSP + off);
      uint4 v1 = *(const uint4*)(z + (size_t)rs[j+1] * WSP + off);
      uint4 v2 = *(const uint4*)(z + (size_t)rs[j+2] * WSP + off);
      uint4 v3 = *(const uint4*)(z + (size_t)rs[j+3] * WSP + off);
      uint4 v4 = *(const uint4*)(z + (size_t)rs[j+4] * WSP + off);
      uint4 v5 = *(const uint4*)(z + (size_t)rs[j+5] * WSP + off);
      uint4 v6 = *(const uint4*)(z + (size_t)rs[j+6] * WSP + off);
      uint4 v7 = *(const uint4*)(z + (size_t)rs[j+7] * WSP + off);
      float w0 = ws[j+0], w1 = ws[j+1], w2 = ws[j+2], w3 = ws[j+3];
      float w4 = ws[j+4], w5 = ws[j+5], w6 = ws[j+6], w7 = ws[j+7];
      ACC8W(v0, w0) ACC8W(v1, w1) ACC8W(v2, w2) ACC8W(v3, w3)
      ACC8W(v4, w4) ACC8W(v5, w5) ACC8W(v6, w6) ACC8W(v7, w7)
    }
    if (j + 4 <= cnt){
      uint4 v0 = *(const uint4*)(z + (size_t)rs[j+0] * WSP + off);
      uint4 v1 = *(const uint4*)(z + (size_t)rs[j+1] * WSP + off);
      uint4 v2 = *(const uint4*)(z + (size_t)rs[j+2] * WSP + off);
      uint4 v3 = *(const uint4*)(z + (size_t)rs[j+3] * WSP + off);
      float w0 = ws[j+0], w1 = ws[j+1], w2 = ws[j+2], w3 = ws[j+3];
      ACC8W(v0, w0) ACC8W(v1, w1) ACC8W(v2, w2) ACC8W(v3, w3)
      j += 4;
    }
    for (; j < cnt; ++j){
      const uint4 v = *(const uint4*)(z + (size_t)rs[j] * WSP + off);
      const float w = ws[j];
      ACC8W(v, w)
    }
  }
  float sv[8] = {0.f, 0.f, 0.f, 0.f, 0.f, 0.f, 0.f, 0.f};
  if (sub){
    const uint4 s0 = *(const uint4*)(sub + (size_t)c * WSP + off);
    sv[0]=b2f((unsigned short)s0.x); sv[1]=b2f((unsigned short)(s0.x>>16));
    sv[2]=b2f((unsigned short)s0.y); sv[3]=b2f((unsigned short)(s0.y>>16));
    sv[4]=b2f((unsigned short)s0.z); sv[5]=b2f((unsigned short)(s0.z>>16));
    sv[6]=b2f((unsigned short)s0.w); sv[7]=b2f((unsigned short)(s0.w>>16));
  }
  unsigned int pk[4];
  #pragma unroll
  for (int q = 0; q < 4; ++q){
    float a = scale * acc[2*q]     - sv[2*q];
    float b = scale * acc[2*q + 1] - sv[2*q + 1];
    pk[q] = (unsigned int)f2b(a) | ((unsigned int)f2b(b) << 16);
  }
  *(uint4*)(outz + (size_t)c * WSP + off) = make_uint4(pk[0], pk[1], pk[2], pk[3]);
}

// ---------------- fused final GEMM + relayout: out[b,n,g,t] = relu(...) ----------------
__global__ __launch_bounds__(256) void k_fgemm(const unsigned short* __restrict__ T0n,
                                               const unsigned short* __restrict__ T1n,
                                               const unsigned short* __restrict__ T2n,
                                               const unsigned short* __restrict__ xTn,
                                               const unsigned short* __restrict__ Wh,
                                               const float* __restrict__ bsum,
                                               float* __restrict__ out){
  __shared__ unsigned short As[16384];
  __shared__ unsigned short Ws[8192];
  const int m0 = blockIdx.x * 128;
  const int tid = threadIdx.x, wave = tid >> 6, lane = tid & 63;
  const int fr = lane & 15, rowb = (lane >> 4) * 4;
  const int wr = (wave >> 1) * 64, wc = (wave & 1) * 32;
  #pragma unroll
  for (int it = 0; it < 8; ++it){
    const int row = it * 16 + wave * 4 + (lane >> 4);
    const int g = (lane & 15) ^ (row & 7);
    const int ss = g >> 2, off = (g & 3) * 8;
    const unsigned short* bp = (ss == 0) ? T0n : (ss == 1) ? T1n : (ss == 2) ? T2n : xTn;
    gload16(bp + (size_t)(m0 + row) * FB + off, &As[(it*4 + wave) * 512]);
  }
  #pragma unroll
  for (int it = 0; it < 4; ++it){
    const int row = it * 16 + wave * 4 + (lane >> 4);
    const int g = (lane & 15) ^ (row & 7);
    gload16(Wh + (size_t)row * 128 + g * 8, &Ws[(it*4 + wave) * 512]);
  }
  __syncthreads();
  f32x4 acc[4][2];
  #pragma unroll
  for (int m = 0; m < 4; ++m){ acc[m][0] = 0.f; acc[m][1] = 0.f; }
  #pragma unroll
  for (int kk = 0; kk < 4; ++kk){
    const int ch = kk * 4 + (lane >> 4);
    const int cs = (ch ^ (fr & 7)) * 8;
    sh8 af[4], bf2[2];
    #pragma unroll
    for (int m = 0; m < 4; ++m)
      af[m] = *(const sh8*)&As[(wr + m*16 + fr) * 128 + cs];
    #pragma unroll
    for (int n = 0; n < 2; ++n)
      bf2[n] = *(const sh8*)&Ws[(wc + n*16 + fr) * 128 + cs];
    #pragma unroll
    for (int m = 0; m < 4; ++m)
      #pragma unroll
      for (int n = 0; n < 2; ++n)
        acc[m][n] = __builtin_amdgcn_mfma_f32_16x16x32_bf16(af[m], bf2[n], acc[m][n], 0, 0, 0);
  }
  #pragma unroll
  for (int m = 0; m < 4; ++m){
    const int row4 = m0 + wr + m*16 + rowb;
    const int nn = row4 / 192;
    const int rem = row4 - nn * 192;
    const int b = rem / 24;
    const int t0 = rem - b * 24;
    #pragma unroll
    for (int n = 0; n < 2; ++n){
      const int g = wc + n*16 + fr;
      const float bv = bsum[g];
      float4 v;
      v.x = fmaxf(acc[m][n][0] + bv, 0.f);
      v.y = fmaxf(acc[m][n][1] + bv, 0.f);
      v.z = fmaxf(acc[m][n][2] + bv, 0.f);
      v.w = fmaxf(acc[m][n][3] + bv, 0.f);
      *(float4*)(out + (((size_t)b * NB + nn) * GB + g) * TB + t0) = v;
    }
  }
}

// ---------------- fused constants: Wcat + score-zero (block 0), Vs->bf16 (blocks 1..1024) ----------------
__global__ __launch_bounds__(256) void k_const(const float* __restrict__ Vs,
                                               const float* __restrict__ cW,
                                               const float* __restrict__ cB,
                                               const float* __restrict__ rW,
                                               const float* __restrict__ rB,
                                               unsigned short* __restrict__ Vsh,
                                               unsigned short* __restrict__ Wh,
                                               float* __restrict__ bsum,
                                               float* __restrict__ score){
  if (blockIdx.x == 0){
    for (int i = threadIdx.x; i < 8192; i += 256){
      int g = i >> 7, k = i & 127;
      int s = k >> 5, f = k & 31;
      float v = (s < 3) ? cW[(s * 32 + f) * 64 + g] : rW[g * 32 + f];
      Wh[i] = f2b(v);
    }
    if (threadIdx.x < 64) bsum[threadIdx.x] = cB[threadIdx.x] + rB[threadIdx.x];
    for (int i = threadIdx.x; i < 4608; i += 256) score[i] = 0.f;
  } else {
    int i = ((blockIdx.x - 1) * 256 + threadIdx.x) * 4;
    float4 v = *(const float4*)(Vs + i);
    unsigned short* o = Vsh + i;
    o[0] = f2b(v.x); o[1] = f2b(v.y); o[2] = f2b(v.z); o[3] = f2b(v.w);
  }
}

extern "C" void kernel_launch(void* const* d_in, const int* in_sizes, int n_in,
                              void* d_out, int out_size, void* d_ws, size_t ws_size,
                              hipStream_t stream){
  const float* x  = (const float*)d_in[0];
  const int*   ei = (const int*)d_in[1];
  const float* ew = (const float*)d_in[2];
  const float* Ve = (const float*)d_in[3];
  const float* be = (const float*)d_in[4];
  const float* Vs = (const float*)d_in[5];
  const float* bs = (const float*)d_in[6];
  const float* cW = (const float*)d_in[7];
  const float* cB = (const float*)d_in[8];
  const float* rW = (const float*)d_in[9];
  const float* rB = (const float*)d_in[10];
  float* out = (float*)d_out;

  char* W = (char*)d_ws;
  unsigned short* sigh  = (unsigned short*)(W + 0);          // 16 MB: sig -> later Sh
  unsigned short* Sh    = sigh;
  unsigned short* xTAh  = (unsigned short*)(W + 16777216);   // 12 MB: xTA bf16 -> later T0n
  unsigned short* T0n   = xTAh;
  unsigned short* xTAhT = (unsigned short*)(W + 29360128);   // 12 MB: xTA^T -> later T1n
  unsigned short* T1n   = xTAhT;
  unsigned short* xTn   = (unsigned short*)(W + 41943040);   // 12 MB: x node-major bf16
  unsigned short* xSAh  = (unsigned short*)(W + 54525952);   // 12 MB: xSA bf16 -> later T2n
  unsigned short* T2n   = xSAh;
  unsigned short* C2h   = (unsigned short*)(W + 67108864);   // 16 MB logits
  unsigned short* Vsh   = (unsigned short*)(W + 83886080);   // 2 MB
  unsigned short* Wh    = (unsigned short*)(W + 92274688);   // 16 KB
  float* bsum  = (float*)(W + 92291072);
  float* score = (float*)(W + 92291328);
  float* normv = (float*)(W + 92328192);
  float* deg   = (float*)(W + 92393728);
  int*   cnt   = (int*)(W + 92397824);
  int*   ptr   = (int*)(W + 92401920);
  int*   fill  = (int*)(W + 92406272);
  int*   cidx  = (int*)(W + 92410368);

  hipMemsetAsync(deg, 0, 8192, stream);   // deg + cnt (contiguous)

  // constants + score zeroing (fused)
  k_const<<<1025, 256, 0, stream>>>(Vs, cW, cB, rW, rB, Vsh, Wh, bsum, score);

  // fused pass 1: single read of x -> xTn + Gram score; xTA with inline Eatt
  k_pass1<<<dim3(128, 8), 256, 0, stream>>>(x, xTn, score);
  k_xta2<<<dim3(128, 8), 256, 0, stream>>>(xTn, score, Ve, be, xTAh);
  k_tr<<<dim3(12, 16, 8), 256, 0, stream>>>(xTAh, xTAhT);

  // spatial attention: three bf16 MFMA GEMMs (single-buffer 128x128, swizzle, XCD affinity)
  k_mgemm<1><<<512, 256, 0, stream>>>(xTAh, xTAh, sigh, DB, DB, NB, DB, 8,
                                      (long)NB*DB, (long)NB*DB, (long)NB*NB);
  k_mgemm<2><<<512, 256, 0, stream>>>(Vsh, sigh, C2h, NB, NB, NB, NB, 8,
                                      0L, (long)NB*NB, (long)NB*NB);
  k_softmax_s<<<8192, 256, 0, stream>>>(C2h, bs, Sh);
  k_mgemm<2><<<384, 256, 0, stream>>>(Sh, xTAhT, xSAh, NB, NB, DB, NB, 6,
                                      (long)NB*NB, (long)NB*DB, (long)NB*DB);

  // ChebConv: node-major layout + parallel CSR build + 2 XCD-affine ILP SpMMs
  k_t0n<<<dim3(128, 8), 256, 0, stream>>>(xSAh, T0n);
  k_edge_deg<<<64, 256, 0, stream>>>(ei, ew, deg, cnt);
  k_scan<<<1, 1024, 0, stream>>>(cnt, ptr, fill);
  k_edge_fill<<<64, 256, 0, stream>>>(ei, ew, deg, fill, cidx, normv);
  k_spmm<<<4096, 192, 0, stream>>>(T0n, normv, cidx, ei, ptr, nullptr, 1.f, T1n);
  k_spmm<<<4096, 192, 0, stream>>>(T1n, normv, cidx, ei, ptr, T0n, 2.f, T2n);

  // fused Cheb matmuls + residual + bias + relu + relayout (direct f32 out)
  k_fgemm<<<1536, 256, 0, stream>>>(T0n, T1n, T2n, xTn, Wh, bsum, out);
}